// Round 13
// baseline (442.978 us; speedup 1.0000x reference)
//
#include <hip/hip_runtime.h>
#include <math.h>

#define G 8
#define N0 16384
#define NEDGE (G*N0*8)      // 1048576
#define EPG (NEDGE/G)       // 131072 edges per graph
#define C 128
#define EPS_FA 0.1f
#define SMAX 2048
#define FLAGA (1u<<30)
#define FLAGP (2u<<30)

typedef unsigned short ushort_t;
typedef unsigned int uint_t;

__device__ inline ushort_t f2bf(float f) {
    uint_t u = __float_as_uint(f);
    uint_t r = (u + 0x7FFFu + ((u >> 16) & 1u)) >> 16;
    return (ushort_t)r;
}
__device__ inline uint_t pack2bf(float a, float b) {
    return (uint_t)f2bf(a) | ((uint_t)f2bf(b) << 16);
}
__device__ inline float bflo(uint_t w) { return __uint_as_float(w << 16); }
__device__ inline float bfhi(uint_t w) { return __uint_as_float(w & 0xFFFF0000u); }

// ---------------- layer-0 deg/score LDS histogram + edge local rank ----------------
__global__ void __launch_bounds__(256) k_hist0(const int* __restrict__ ei,
                                               unsigned int* __restrict__ bh,
                                               ushort_t* __restrict__ lrank) {
    __shared__ unsigned int h[N0];
    int t = threadIdx.x;
    for (int i = t; i < N0; i += 256) h[i] = 0;
    __syncthreads();
    int base = blockIdx.x * 8192;
    int gbase = (blockIdx.x >> 4) * N0;
    for (int i = t; i < 8192; i += 256) {
        int s = ei[base + i] - gbase;
        int d = ei[NEDGE + base + i] - gbase;
        unsigned int old = atomicAdd(&h[d], 1u);
        lrank[base + i] = (ushort_t)(old & 0xFFFFu);
        atomicAdd(&h[s], 0x10000u);
    }
    __syncthreads();
    unsigned int* o = bh + (size_t)blockIdx.x * N0;
    for (int i = t; i < N0; i += 256) o[i] = h[i];
}

// ---------------- alar + bf16 convert + zero pooled/scanstate ----------------
__global__ void __launch_bounds__(256) k_alar(const float* __restrict__ x,
                       const float* __restrict__ attl, const float* __restrict__ attr,
                       float* __restrict__ al, float* __restrict__ ar,
                       ushort_t* __restrict__ xb, float* __restrict__ pooled,
                       unsigned int* __restrict__ scanstate) {
    int gidx = blockIdx.x * 256 + threadIdx.x;
    if (gidx < 3072) pooled[gidx] = 0.0f;
    if (gidx < 1536) scanstate[gidx] = 0u;
    int wid = gidx >> 6, lane = gidx & 63;
    float2 v  = ((const float2*)(x + (size_t)wid * C))[lane];
    ((uint_t*)(xb + (size_t)wid * C))[lane] = pack2bf(v.x, v.y);
    float2 l2 = ((const float2*)attl)[lane];
    float2 r2 = ((const float2*)attr)[lane];
    float sl = v.x * l2.x + v.y * l2.y;
    float sr = v.x * r2.x + v.y * r2.y;
    for (int o = 32; o >= 1; o >>= 1) { sl += __shfl_xor(sl, o); sr += __shfl_xor(sr, o); }
    if (lane == 0) { al[wid] = sl; ar[wid] = sr; }
}

// ---------------- fused scan: sumdeg + lookback prefix + node records ----------------
__global__ void __launch_bounds__(256) k_scan(
        unsigned int* __restrict__ bh, int shiftBins, int nsub,
        const float* __restrict__ al, const float* __restrict__ ar,
        const int* __restrict__ oidx,
        int* __restrict__ score, float4* __restrict__ fillinfo,
        int4* __restrict__ nodeinfo,
        unsigned char* __restrict__ keep, int* __restrict__ nmap,
        unsigned int* __restrict__ state) {
    __shared__ int part[256];
    __shared__ int sbase;
    int b = blockIdx.x, t = threadIdx.x;
    int i = b * 256 + t;
    int bins = 1 << shiftBins;
    int g = i >> shiftBins, u = i & (bins - 1);
    unsigned int* p = bh + ((size_t)(g * nsub) << shiftBins) + u;
    unsigned int run = 0; int as = 0;
    for (int bb = 0; bb < nsub; bb++) {
        unsigned int w = p[(size_t)bb << shiftBins];
        p[(size_t)bb << shiftBins] = run;
        run += w & 0xFFFFu; as += (int)(w >> 16);
    }
    int deg = (int)run;
    score[i] = as;
    // block inclusive scan of deg
    part[t] = deg; __syncthreads();
    for (int o = 1; o < 256; o <<= 1) {
        int val = part[t];
        int add = (t >= o) ? part[t - o] : 0;
        __syncthreads();
        part[t] = val + add;
        __syncthreads();
    }
    int incl = part[t];
    int S = part[255];
    // decoupled lookback (first wave)
    if (t < 64) {
        if (b == 0) {
            if (t == 0) { sbase = 0; __threadfence(); atomicExch(&state[0], FLAGP | (unsigned)S); }
        } else {
            if (t == 0) { __threadfence(); atomicExch(&state[b], FLAGA | (unsigned)S); }
            int base = 0;
            int p0 = b - 1;
            while (true) {
                int idx = p0 - (int)t;
                unsigned int st;
                if (idx >= 0) {
                    do { st = atomicAdd(&state[idx], 0u); } while ((st >> 30) == 0);
                } else st = FLAGP;
                unsigned long long pm = __ballot((st >> 30) == 2);
                bool anyP = (pm != 0ull);
                int firstP = anyP ? (int)(__ffsll((long long)pm) - 1) : 64;
                int contrib = ((int)t <= firstP) ? (int)(st & 0x3FFFFFFFu) : 0;
                for (int o2 = 32; o2 >= 1; o2 >>= 1) contrib += __shfl_xor(contrib, o2);
                base += contrib;
                if (anyP) break;
                p0 -= 64;
            }
            if (t == 0) {
                sbase = base;
                __threadfence(); atomicExch(&state[b], FLAGP | (unsigned)(base + S));
            }
        }
    }
    __syncthreads();
    int rp = sbase + incl - deg;
    float df = (float)deg + 1.0f;
    float di = rsqrtf(df);
    float a = al[i], r = ar[i];
    float sc = di * di * tanhf(a + r);
    int o = oidx ? oidx[i] : i;
    fillinfo[i] = make_float4(di, a, r, __int_as_float(rp));
    nodeinfo[i] = make_int4(rp, deg, __float_as_int(sc), o);
    keep[i] = 0; nmap[i] = 0;
}

// ---------------- fused: topk score hist (blocks < histBlocks) + CSR fill ---------
__global__ void __launch_bounds__(256) k_fill_hist(
        const int* __restrict__ src, const int* __restrict__ dst,
        const unsigned char* __restrict__ em,
        const float4* __restrict__ fillinfo,
        const unsigned int* __restrict__ bpre,
        const ushort_t* __restrict__ lrank, int2* __restrict__ edges,
        int ebShift, int nsubShift, int binShift,
        const int* __restrict__ score, int npg, int nb,
        int* __restrict__ blockhist, int histBlocks) {
    __shared__ int lh[SMAX];
    int t = threadIdx.x;
    if ((int)blockIdx.x < histBlocks) {
        int g = blockIdx.x / nb, b = blockIdx.x % nb;
        for (int s = t; s < SMAX; s += 256) lh[s] = 0;
        __syncthreads();
        int s = score[g * npg + b * 256 + t];
        if (s > SMAX - 1) s = SMAX - 1;
        atomicAdd(&lh[s], 1);
        __syncthreads();
        int* outp = blockhist + ((size_t)g * nb + b) * SMAX;
        for (int i = t; i < SMAX; i += 256) outp[i] = lh[i];
    } else {
        int fb = blockIdx.x - histBlocks;
        int gph = fb & 7, chunk = fb >> 3;
        int e = gph * EPG + chunk * 256 + t;
        if (em && !em[e]) return;
        int s = src[e], d = dst[e];
        float4 fs = fillinfo[s];
        float4 fd = fillinfo[d];
        float cf = fs.x * fd.x * tanhf(fd.y + fs.z);
        int b = e >> ebShift;
        int gb = (b >> nsubShift) << binShift;
        int slot = __float_as_int(fd.w)
                 + (int)bpre[((size_t)b << binShift) + (d - gb)] + (int)lrank[e];
        edges[slot] = make_int2(s, __float_as_int(cf));
    }
}

// ---------------- fused: binprefix (blocks < bpBlocks) + CSR gather messages ------
#define ACC4(W, CF) { a0 += (CF) * bflo((W).x); a1 += (CF) * bfhi((W).x); \
                      a2 += (CF) * bflo((W).y); a3 += (CF) * bfhi((W).y); }
__global__ void __launch_bounds__(256) k_msg_bp(
        const int4* __restrict__ nodeinfo,
        const int2* __restrict__ edges,
        const ushort_t* __restrict__ cur, const ushort_t* __restrict__ xb,
        ushort_t* __restrict__ h, float* __restrict__ pb, int npg,
        int* __restrict__ blockhist, int* __restrict__ histT, int nb, int bpBlocks) {
    __shared__ float pm[8 * 128];
    __shared__ int tile[4096];
    int t = threadIdx.x;
    if ((int)blockIdx.x < bpBlocks) {
        int g = blockIdx.x >> 5, ch = blockIdx.x & 31;
        int s0 = ch * 64;
        int* bg = blockhist + (size_t)g * nb * SMAX;
        int tot = nb * 64;
        for (int i = t; i < tot; i += 256)
            tile[i] = bg[(size_t)(i >> 6) * SMAX + s0 + (i & 63)];
        __syncthreads();
        if (t < 64) {
            int acc = 0;
            for (int b = 0; b < nb; b++) {
                int idx = b * 64 + t;
                int v = tile[idx]; tile[idx] = acc; acc += v;
            }
            histT[g * SMAX + s0 + t] = acc;
        }
        __syncthreads();
        for (int i = t; i < tot; i += 256)
            bg[(size_t)(i >> 6) * SMAX + s0 + (i & 63)] = tile[i];
        return;
    }
    int mb   = blockIdx.x - bpBlocks;
    int g    = mb & 7;
    int ib   = mb >> 3;
    int sub  = t >> 5;
    int lane = t & 31;
    int v = g * npg + ib * 8 + sub;
    int4 ni = nodeinfo[v];
    int rs = ni.x, deg = ni.y;
    float sc = __int_as_float(ni.z);
    int o = ni.w;
    uint2 cw = ((const uint2*)(cur + (size_t)v * C))[lane];
    uint2 xw = ((const uint2*)(xb  + (size_t)o * C))[lane];
    float a0 = 0.0f, a1 = 0.0f, a2 = 0.0f, a3 = 0.0f;
    for (int j0 = 0; j0 < deg; j0 += 32) {
        int cnt = deg - j0; if (cnt > 32) cnt = 32;
        int last = cnt - 1;
        int2 er = edges[rs + j0 + (lane < last ? lane : last)];
        uint2 w0, w1, w2, w3;
        {
            int s0 = __shfl(er.x, 0, 32);
            w0 = ((const uint2*)(cur + (size_t)s0 * C))[lane];
            int s1 = __shfl(er.x, 1 < last ? 1 : last, 32);
            w1 = ((const uint2*)(cur + (size_t)s1 * C))[lane];
            int s2 = __shfl(er.x, 2 < last ? 2 : last, 32);
            w2 = ((const uint2*)(cur + (size_t)s2 * C))[lane];
            int s3 = __shfl(er.x, 3 < last ? 3 : last, 32);
            w3 = ((const uint2*)(cur + (size_t)s3 * C))[lane];
        }
        int j = 0;
        for (; j + 4 <= cnt; j += 4) {
            float cf0 = __int_as_float(__shfl(er.y, j, 32));
            ACC4(w0, cf0);
            int sn0 = __shfl(er.x, (j + 4) < last ? (j + 4) : last, 32);
            w0 = ((const uint2*)(cur + (size_t)sn0 * C))[lane];
            float cf1 = __int_as_float(__shfl(er.y, j + 1, 32));
            ACC4(w1, cf1);
            int sn1 = __shfl(er.x, (j + 5) < last ? (j + 5) : last, 32);
            w1 = ((const uint2*)(cur + (size_t)sn1 * C))[lane];
            float cf2 = __int_as_float(__shfl(er.y, j + 2, 32));
            ACC4(w2, cf2);
            int sn2 = __shfl(er.x, (j + 6) < last ? (j + 6) : last, 32);
            w2 = ((const uint2*)(cur + (size_t)sn2 * C))[lane];
            float cf3 = __int_as_float(__shfl(er.y, j + 3, 32));
            ACC4(w3, cf3);
            int sn3 = __shfl(er.x, (j + 7) < last ? (j + 7) : last, 32);
            w3 = ((const uint2*)(cur + (size_t)sn3 * C))[lane];
        }
        if (j < cnt)     { float cf = __int_as_float(__shfl(er.y, j,     32)); ACC4(w0, cf); }
        if (j + 1 < cnt) { float cf = __int_as_float(__shfl(er.y, j + 1, 32)); ACC4(w1, cf); }
        if (j + 2 < cnt) { float cf = __int_as_float(__shfl(er.y, j + 2, 32)); ACC4(w2, cf); }
    }
    float r0 = fmaxf(a0 + sc * bflo(cw.x) + EPS_FA * bflo(xw.x), 0.0f);
    float r1 = fmaxf(a1 + sc * bfhi(cw.x) + EPS_FA * bfhi(xw.x), 0.0f);
    float r2 = fmaxf(a2 + sc * bflo(cw.y) + EPS_FA * bflo(xw.y), 0.0f);
    float r3 = fmaxf(a3 + sc * bfhi(cw.y) + EPS_FA * bfhi(xw.y), 0.0f);
    uint2 hw; hw.x = pack2bf(r0, r1); hw.y = pack2bf(r2, r3);
    ((uint2*)(h + (size_t)v * C))[lane] = hw;
    float4 rr = make_float4(r0, r1, r2, r3);
    ((float4*)(pm + sub * 128))[lane] = rr;
    __syncthreads();
    if (t < 128) {
        float m = pm[t];
        for (int s = 1; s < 8; s++) m = fmaxf(m, pm[s * 128 + t]);
        pb[(size_t)mb * 128 + t] = m;
    }
}

// ---------------- fused: rank (blocks < rankBlocks) + pool partial reduce ---------
__global__ void __launch_bounds__(256) k_pool_rank(
        const float* __restrict__ pb, float* __restrict__ pooled, int layer,
        const int* __restrict__ score, const int* __restrict__ blockhist,
        const int* __restrict__ hist, int npg, int nb, int k,
        unsigned char* __restrict__ keep, int* __restrict__ nmap,
        int* __restrict__ perm, int rankBlocks) {
    __shared__ int bp[SMAX];
    __shared__ int part[256];
    __shared__ int cs[256];
    __shared__ float sm[256];
    int t = threadIdx.x;
    if ((int)blockIdx.x < rankBlocks) {
        int g = blockIdx.x / nb, b = blockIdx.x % nb;
        const int* hg = hist + g * SMAX;
        int v[8]; int smv = 0;
        for (int i = 0; i < 8; i++) { v[i] = hg[SMAX - 1 - (t * 8 + i)]; smv += v[i]; }
        part[t] = smv; __syncthreads();
        for (int o = 1; o < 256; o <<= 1) {
            int val = part[t];
            int add = (t >= o) ? part[t - o] : 0;
            __syncthreads();
            part[t] = val + add;
            __syncthreads();
        }
        int run = (t == 0) ? 0 : part[t - 1];
        for (int i = 0; i < 8; i++) { bp[SMAX - 1 - (t * 8 + i)] = run; run += v[i]; }
        int vv = b * 256 + t;
        int s = score[g * npg + vv];
        if (s > SMAX - 1) s = SMAX - 1;
        cs[t] = s;
        __syncthreads();
        int cnt = 0;
        for (int u = 0; u < t; u++) cnt += (cs[u] == s);
        int pos = bp[s] + blockhist[((size_t)g * nb + b) * SMAX + s] + cnt;
        if (pos < k) {
            int vg = g * npg + vv;
            int nid = g * k + pos;
            keep[vg] = 1; nmap[vg] = nid; perm[nid] = vg;
        }
    } else {
        int pr = blockIdx.x - rankBlocks;
        int g = pr & 7, ch = pr >> 3;
        int c = t & 127, half = t >> 7;
        float m = 0.0f;
        for (int i = 0; i < 32; i++) {
            int r = ch * 64 + half * 32 + i;
            m = fmaxf(m, pb[(size_t)(g + 8 * r) * 128 + c]);
        }
        sm[t] = m;
        __syncthreads();
        if (t < 128) {
            float mm = fmaxf(sm[t], sm[t + 128]);
            atomicMax((unsigned int*)&pooled[g * 384 + layer * 128 + c], __float_as_uint(mm));
        }
    }
}

// ---------------- fused: remap+hist (blocks 0..255) + gather kept nodes -----------
__global__ void __launch_bounds__(256) k_gather_remap(
        const ushort_t* __restrict__ h, const int* __restrict__ perm,
        const int* __restrict__ oidx,
        const float* __restrict__ attlN, const float* __restrict__ attrN,
        ushort_t* __restrict__ curN, int* __restrict__ oidxN,
        float* __restrict__ al, float* __restrict__ ar, int m,
        const int* __restrict__ inS, const int* __restrict__ inD,
        const unsigned char* __restrict__ inEm,
        int* __restrict__ src, int* __restrict__ dst, unsigned char* __restrict__ em,
        const unsigned char* __restrict__ keep, const int* __restrict__ nmap,
        unsigned int* __restrict__ bh, ushort_t* __restrict__ lrank, int kN) {
    __shared__ unsigned int hh[8192];
    int t = threadIdx.x;
    if ((int)blockIdx.x < 256) {
        for (int i = t; i < kN; i += 256) hh[i] = 0;
        __syncthreads();
        int base = blockIdx.x * 4096;
        int gb = (blockIdx.x >> 5) * kN;
        for (int i = t; i < 4096; i += 256) {
            int e = base + i;
            int s = inS[e], d = inD[e];
            bool ok = (!inEm || inEm[e]) && keep[s] && keep[d];
            if (ok) {
                int ns = nmap[s], nd = nmap[d];
                src[e] = ns; dst[e] = nd; em[e] = 1;
                unsigned int old = atomicAdd(&hh[nd - gb], 1u);
                lrank[e] = (ushort_t)(old & 0xFFFFu);
                atomicAdd(&hh[ns - gb], 0x10000u);
            } else { src[e] = 0; dst[e] = 0; em[e] = 0; }
        }
        __syncthreads();
        unsigned int* o = bh + (size_t)blockIdx.x * kN;
        for (int i = t; i < kN; i += 256) o[i] = hh[i];
    } else {
        int i = (blockIdx.x - 256) * 256 + t;
        int j = i >> 5, c4 = i & 31;
        int p = perm[j];
        uint2 w = ((const uint2*)(h + (size_t)p * C))[c4];
        ((uint2*)(curN + (size_t)j * C))[c4] = w;
        float f0 = bflo(w.x), f1 = bfhi(w.x), f2 = bflo(w.y), f3 = bfhi(w.y);
        float4 l4 = ((const float4*)attlN)[c4];
        float4 r4 = ((const float4*)attrN)[c4];
        float sl = f0 * l4.x + f1 * l4.y + f2 * l4.z + f3 * l4.w;
        float sr = f0 * r4.x + f1 * r4.y + f2 * r4.z + f3 * r4.w;
        for (int o = 16; o >= 1; o >>= 1) { sl += __shfl_xor(sl, o); sr += __shfl_xor(sr, o); }
        if (c4 == 0) {
            al[j] = sl; ar[j] = sr;
            oidxN[j] = oidx ? oidx[p] : p;
        }
    }
}

// ---------------- GRU head, stage A ----------------
__global__ void __launch_bounds__(256) k_gi(const float* __restrict__ pooled,
                                            const float* __restrict__ wih,
                                            const float* __restrict__ bih,
                                            float* __restrict__ gi) {
    int g = blockIdx.y;
    int row = blockIdx.x * 4 + (threadIdx.x >> 6);
    int lane = threadIdx.x & 63;
    const float* w = wih + (size_t)row * 384;
    const float* f = pooled + g * 384;
    float s = 0.0f;
    #pragma unroll
    for (int i = 0; i < 6; i++) s += w[i * 64 + lane] * f[i * 64 + lane];
    for (int o = 32; o >= 1; o >>= 1) s += __shfl_xor(s, o);
    if (lane == 0) gi[g * 768 + row] = s + bih[row];
}

// ---------------- GRU head, stage B ----------------
__global__ void __launch_bounds__(256) k_gru_fin(const float* __restrict__ gi,
        const float* __restrict__ bhh, const float* __restrict__ wfin,
        const float* __restrict__ bfin, const float* __restrict__ wroot,
        const float* __restrict__ broot, const float* __restrict__ rootv,
        const float* __restrict__ alphap, float* __restrict__ out) {
    int g = blockIdx.x, t = threadIdx.x;
    __shared__ float hg[256];
    {
        float r  = 1.0f / (1.0f + expf(-(gi[g * 768 + t]       + bhh[t])));
        float z  = 1.0f / (1.0f + expf(-(gi[g * 768 + 256 + t] + bhh[256 + t])));
        float nc = tanhf(gi[g * 768 + 512 + t] + r * bhh[512 + t]);
        hg[t] = (1.0f - z) * nc;
    }
    __syncthreads();
    float a = alphap[0];
    int wv = t >> 6, lane = t & 63;
    const float* rg = rootv + (size_t)g * 128;
    for (int oo = 0; oo < 32; oo++) {
        int o = wv * 32 + oo;
        const float* wf = wfin + (size_t)o * 256;
        float sf = wf[lane] * hg[lane] + wf[64 + lane] * hg[64 + lane]
                 + wf[128 + lane] * hg[128 + lane] + wf[192 + lane] * hg[192 + lane];
        const float* wr = wroot + (size_t)o * 128;
        float sr = wr[lane] * rg[lane] + wr[64 + lane] * rg[64 + lane];
        float s = a * sf + (1.0f - a) * sr;
        for (int sh = 32; sh >= 1; sh >>= 1) s += __shfl_xor(s, sh);
        if (lane == 0)
            out[g * 128 + o] = s + a * bfin[o] + (1.0f - a) * broot[o];
    }
}

extern "C" void kernel_launch(void* const* d_in, const int* in_sizes, int n_in,
                              void* d_out, int out_size, void* d_ws, size_t ws_size,
                              hipStream_t stream) {
    const float* x      = (const float*)d_in[0];
    const int*   ei     = (const int*)d_in[1];
    const float* rootv  = (const float*)d_in[3];
    const float* att_l  = (const float*)d_in[4];
    const float* att_r  = (const float*)d_in[5];
    const float* w_ih   = (const float*)d_in[6];
    const float* b_ih   = (const float*)d_in[8];
    const float* b_hh   = (const float*)d_in[9];
    const float* w_fin  = (const float*)d_in[10];
    const float* b_fin  = (const float*)d_in[11];
    const float* w_root = (const float*)d_in[12];
    const float* b_root = (const float*)d_in[13];
    const float* alphap = (const float*)d_in[14];
    float* out = (float*)d_out;

    char* wsb = (char*)d_ws;
    size_t off = 0;
    auto alloc = [&](size_t bytes) -> char* {
        char* p = wsb + off; off += (bytes + 255) & ~(size_t)255; return p;
    };
    ushort_t* xb   = (ushort_t*)alloc((size_t)131072 * C * 2);
    ushort_t* bufH = (ushort_t*)alloc((size_t)131072 * C * 2);
    ushort_t* bufC = (ushort_t*)alloc((size_t)65536  * C * 2);
    int*   srcA   = (int*)alloc((size_t)NEDGE * 4);
    int*   dstA   = (int*)alloc((size_t)NEDGE * 4);
    unsigned char* emask = (unsigned char*)alloc(NEDGE);
    int2*  edges  = (int2*)alloc((size_t)NEDGE * 8);
    ushort_t* lrank = (ushort_t*)alloc((size_t)NEDGE * 2);
    float* al     = (float*)alloc(131072 * 4);
    float* ar     = (float*)alloc(131072 * 4);
    int*   score  = (int*)alloc(131072 * 4);
    float4* fillinfo = (float4*)alloc((size_t)131072 * 16);
    int4*   nodeinfo = (int4*)alloc((size_t)131072 * 16);
    unsigned char* keep = (unsigned char*)alloc(131072);
    int*   nmap   = (int*)alloc(131072 * 4);
    int*   perm   = (int*)alloc(65536 * 4);
    int*   oidxA  = (int*)alloc(65536 * 4);
    int*   oidxB  = (int*)alloc(32768 * 4);
    float* pooled = (float*)alloc(G * 384 * 4);
    float* giBuf  = (float*)alloc(G * 768 * 4);
    unsigned int* scanstate = (unsigned int*)alloc(1536 * 4);
    int*   blockhist = (int*)alloc((size_t)G * 64 * SMAX * 4);
    int*   histT  = (int*)alloc((size_t)G * SMAX * 4);
    unsigned int* bh = (unsigned int*)alloc((size_t)128 * N0 * 4);
    float* pb = (float*)bh;   // pool partials alias bh (disjoint lifetimes)

    k_hist0<<<128, 256, 0, stream>>>(ei, bh, lrank);
    k_alar<<<32768, 256, 0, stream>>>(x, att_l, att_r, al, ar, xb, pooled, scanstate);

    const int ns[3]   = {131072, 65536, 32768};
    const int npgs[3] = {16384, 8192, 4096};
    const int ks[3]   = {8192, 4096, 0};
    const int shifts[3] = {14, 13, 12};
    const int stoff[3]  = {0, 512, 768};

    for (int l = 0; l < 3; l++) {
        int n = ns[l], npg = npgs[l], k = ks[l];
        const ushort_t* cur = (l == 0) ? xb : bufC;
        const int* oidx = (l == 0) ? nullptr : (l == 1 ? oidxA : oidxB);
        int* oidxN = (l == 0) ? oidxA : oidxB;
        const int* eS = (l == 0) ? ei : srcA;
        const int* eD = (l == 0) ? ei + NEDGE : dstA;
        const unsigned char* eM = (l == 0) ? nullptr : emask;
        int ebShift   = (l == 0) ? 13 : 12;
        int nsubShift = (l == 0) ? 4  : 5;
        int nsub      = (l == 0) ? 16 : 32;
        int binShift  = shifts[l];
        int nb = npg / 256;

        k_scan<<<n / 256, 256, 0, stream>>>(bh, binShift, nsub, al, ar, oidx,
                                            score, fillinfo, nodeinfo, keep, nmap,
                                            scanstate + stoff[l]);

        int histBlocks = (l < 2) ? G * nb : 0;
        k_fill_hist<<<histBlocks + NEDGE / 256, 256, 0, stream>>>(
            eS, eD, eM, fillinfo, bh, lrank, edges,
            ebShift, nsubShift, binShift, score, npg, nb, blockhist, histBlocks);

        int bpBlocks = (l < 2) ? 256 : 0;
        k_msg_bp<<<bpBlocks + n / 8, 256, 0, stream>>>(
            nodeinfo, edges, cur, xb, bufH, pb, npg,
            blockhist, histT, nb, bpBlocks);

        int rankBlocks = (l < 2) ? G * nb : 0;
        k_pool_rank<<<rankBlocks + npg / 64, 256, 0, stream>>>(
            pb, pooled, l, score, blockhist, histT, npg, nb, k,
            keep, nmap, perm, rankBlocks);

        if (l < 2) {
            int m = G * k;
            k_gather_remap<<<256 + m / 8, 256, 0, stream>>>(
                bufH, perm, oidx, att_l + (l + 1) * C, att_r + (l + 1) * C,
                bufC, oidxN, al, ar, m,
                eS, eD, eM, srcA, dstA, emask, keep, nmap, bh, lrank, k);
        }
    }

    k_gi<<<dim3(192, G), 256, 0, stream>>>(pooled, w_ih, b_ih, giBuf);
    k_gru_fin<<<G, 256, 0, stream>>>(giBuf, b_hh, w_fin, b_fin, w_root, b_root,
                                     rootv, alphap, out);
}